// Round 5
// baseline (45.717 us; speedup 1.0000x reference)
//
#include <hip/hip_runtime.h>

#define V 64
#define W 5
#define G 80
#define O 80
#define NROT 16
#define GPAD 96
#define EPSV 1e-5f
#define NLOG2E (-1.4426950408889634f)

// d_ws layout (shorts):
//   [0, WSB_SHORTS)                : packed bf16 Wc B-frags [75][64][8]
//   [WSB_SHORTS, ...)              : bf16 descT [np][W][NROT][GPAD]
#define WSB_SHORTS (75 * 64 * 8)

using bf16x8 = __attribute__((ext_vector_type(8))) short;
using f32x4  = __attribute__((ext_vector_type(4))) float;

__device__ __forceinline__ unsigned short f2bf(float x) {
    unsigned u = __float_as_uint(x);
    unsigned r = (u + 0x7FFFu + ((u >> 16) & 1u)) >> 16;   // RNE
    return (unsigned short)r;
}

// ============================================================================
// Kernel 1: desc_kernel — one block per point (640 thr = 10 waves),
// thread = (g = tid%80, j = tid/80 in 0..7 -> k-pair 2j,2j+1).
// Blocks with blockIdx >= np pack Wc into bf16 B-fragments instead.
// ============================================================================
__global__ __launch_bounds__(640) void desc_kernel(
    const float* __restrict__ feat,      // [NP][V][W]
    const float* __restrict__ rho,       // [NP][V]
    const float* __restrict__ theta,     // [NP][V]
    const float* __restrict__ mask,      // [NP][V]
    const float* __restrict__ mu_rho,    // [W][G]
    const float* __restrict__ mu_theta,  // [W][G]
    const float* __restrict__ sig_rho,   // [W][G]
    const float* __restrict__ sig_theta, // [W][G]
    const float* __restrict__ Wc,        // [W][G][O]
    unsigned short* __restrict__ ws,
    int np)
{
    const int tid = threadIdx.x;

    // ---- tail blocks: pack Wc into B-frags (frag f, lane l) ----
    if ((int)blockIdx.x >= np) {
        int idx = ((int)blockIdx.x - np) * 640 + tid;
        int f = idx >> 6, l = idx & 63;
        if (f < 75) {
            int w  = f / 15, r = f % 15;
            int ks = r / 5,  nt = r % 5;
            int g0 = ks * 32 + ((l >> 4) << 3);
            int o  = nt * 16 + (l & 15);
            unsigned short v[8];
            #pragma unroll
            for (int i = 0; i < 8; ++i) {
                int g = g0 + i;
                v[i] = (g < G) ? f2bf(Wc[(w * G + g) * O + o]) : (unsigned short)0;
            }
            *(uint4*)(ws + ((size_t)f * 64 + l) * 8) = *(const uint4*)v;
        }
        return;
    }

    __shared__ float s_pt[V][8];         // f0..f4, rho, mrk, 0
    __shared__ float s_th[V][NROT];      // rotated theta per (v,k)

    const int p = blockIdx.x;
    const int g = tid % G;    // 0..79
    const int j = tid / G;    // 0..7 (k-pair index)

    unsigned short* dp = ws + WSB_SHORTS + (size_t)p * (W * NROT * GPAD);

    // ---- stage 1: stage point data; zero desc g-pad (stale ws may be Inf/NaN) ----
    if (tid < V * W) {
        int v = tid / W, w = tid % W;
        s_pt[v][w] = feat[p * V * W + tid];
    }
    if (tid < V) {
        s_pt[tid][5] = rho[p * V + tid];
        s_pt[tid][6] = (mask[p * V + tid] != 0.0f) ? 0.0f : -1e30f;
        s_pt[tid][7] = 0.0f;
    }
    if (tid < W * NROT * 8) {            // pad cols 80..95 as 8 u32 per row
        int row = tid >> 3, c = tid & 7;
        *(unsigned*)(dp + row * GPAD + 80 + 2 * c) = 0u;
    }
    const float kstep = 0.39269908169872414f;      // 2*pi/16
    const float two_pi = 6.283185307179586f;
    const float inv_two_pi = 0.15915494309189535f;
    for (int i = tid; i < V * NROT; i += 640) {
        int v = i >> 4, k = i & 15;
        float x = theta[p * V + v] + (float)k * kstep;
        x = x - floorf(x * inv_two_pi) * two_pi;   // jnp.mod(x, 2pi)
        s_th[v][k] = x;
    }

    // uniformity check (rows 1..4 each checked twice across j)
    const int wchk = 1 + (j & 3);
    int pred = (mu_rho  [wchk * G + g] == mu_rho  [g]) &&
               (mu_theta[wchk * G + g] == mu_theta[g]) &&
               (sig_rho [wchk * G + g] == sig_rho [g]) &&
               (sig_theta[wchk * G + g] == sig_theta[g]);
    const int uni = __syncthreads_and(pred);

    if (uni) {
        // fast path: gaussian independent of w -> one exp serves 5 channels
        const float mu_r = mu_rho[g];
        const float sr   = sig_rho[g];
        const float c_sr = NLOG2E / (sr * sr + EPSV);
        const float mu_t = mu_theta[g];
        const float st   = sig_theta[g];
        const float c_st = NLOG2E / (st * st + EPSV);
        const float b_t  = -2.0f * c_st * mu_t;
        const float c0   = c_st * mu_t * mu_t;

        float den0 = 0.f, den1 = 0.f;
        float num0[5], num1[5];
        #pragma unroll
        for (int w = 0; w < W; ++w) { num0[w] = 0.f; num1[w] = 0.f; }

        #pragma unroll 4
        for (int v = 0; v < V; ++v) {
            float4 flo = *(const float4*)(&s_pt[v][0]);   // f0..f3
            float4 fhi = *(const float4*)(&s_pt[v][4]);   // f4, rho, mrk, 0
            float dr   = fhi.y - mu_r;
            float argc = fmaf(dr * dr, c_sr, fhi.z) + c0; // rho + mask + c0
            float2 th2 = *(const float2*)(&s_th[v][2 * j]);

            float h0 = fmaf(c_st, th2.x, b_t);
            float e0 = __builtin_amdgcn_exp2f(fmaf(h0, th2.x, argc));
            den0 += e0;
            num0[0] = fmaf(e0, flo.x, num0[0]);
            num0[1] = fmaf(e0, flo.y, num0[1]);
            num0[2] = fmaf(e0, flo.z, num0[2]);
            num0[3] = fmaf(e0, flo.w, num0[3]);
            num0[4] = fmaf(e0, fhi.x, num0[4]);

            float h1 = fmaf(c_st, th2.y, b_t);
            float e1 = __builtin_amdgcn_exp2f(fmaf(h1, th2.y, argc));
            den1 += e1;
            num1[0] = fmaf(e1, flo.x, num1[0]);
            num1[1] = fmaf(e1, flo.y, num1[1]);
            num1[2] = fmaf(e1, flo.z, num1[2]);
            num1[3] = fmaf(e1, flo.w, num1[3]);
            num1[4] = fmaf(e1, fhi.x, num1[4]);
        }
        float rd0 = __builtin_amdgcn_rcpf(den0 + EPSV);
        float rd1 = __builtin_amdgcn_rcpf(den1 + EPSV);
        #pragma unroll
        for (int w = 0; w < W; ++w) {
            dp[(w * NROT + 2 * j    ) * GPAD + g] = f2bf(num0[w] * rd0);
            dp[(w * NROT + 2 * j + 1) * GPAD + g] = f2bf(num1[w] * rd1);
        }
    } else {
        // generic path: per-w gaussians (correctness fallback)
        #pragma unroll 1
        for (int w = 0; w < W; ++w) {
            const float mu_r = mu_rho[w * G + g];
            const float sr   = sig_rho[w * G + g];
            const float c_sr = NLOG2E / (sr * sr + EPSV);
            const float mu_t = mu_theta[w * G + g];
            const float st   = sig_theta[w * G + g];
            const float c_st = NLOG2E / (st * st + EPSV);
            float den0 = 0.f, den1 = 0.f, nm0 = 0.f, nm1 = 0.f;
            for (int v = 0; v < V; ++v) {
                float rv  = s_pt[v][5];
                float mrk = s_pt[v][6];
                float fw  = s_pt[v][w];
                float dr = rv - mu_r;
                float argr = fmaf(dr * dr, c_sr, mrk);
                float2 th2 = *(const float2*)(&s_th[v][2 * j]);
                float t0 = th2.x - mu_t;
                float e0 = __builtin_amdgcn_exp2f(fmaf(t0 * t0, c_st, argr));
                den0 += e0; nm0 = fmaf(e0, fw, nm0);
                float t1 = th2.y - mu_t;
                float e1 = __builtin_amdgcn_exp2f(fmaf(t1 * t1, c_st, argr));
                den1 += e1; nm1 = fmaf(e1, fw, nm1);
            }
            dp[(w * NROT + 2 * j    ) * GPAD + g] =
                f2bf(nm0 * __builtin_amdgcn_rcpf(den0 + EPSV));
            dp[(w * NROT + 2 * j + 1) * GPAD + g] =
                f2bf(nm1 * __builtin_amdgcn_rcpf(den1 + EPSV));
        }
    }
}

// ============================================================================
// Kernel 2: out_kernel — one wave per (p,w): C[16k x 80o] = descT * Wc,
// max over k (intra-reg + shfl_xor), + bias. 256 thr = 4 waves, no LDS.
// ============================================================================
__global__ __launch_bounds__(256) void out_kernel(
    const unsigned short* __restrict__ ws,
    const float* __restrict__ bc,        // [W][O]
    float* __restrict__ out,             // [NP][W][O]
    int np)
{
    const int tid = threadIdx.x;
    const int l   = tid & 63;
    const int idx = blockIdx.x * 4 + (tid >> 6);
    if (idx >= np * W) return;
    const int p = idx / W, w = idx % W;

    const unsigned short* dbase =
        ws + WSB_SHORTS + (size_t)p * (W * NROT * GPAD) + w * (NROT * GPAD);

    // A-frags: lane l holds A[m = l&15][g = ks*32 + (l>>4)*8 + i]
    bf16x8 afrag[3];
    #pragma unroll
    for (int ks = 0; ks < 3; ++ks)
        afrag[ks] = *(const bf16x8*)(dbase + (l & 15) * GPAD + ks * 32 +
                                     ((l >> 4) << 3));

    #pragma unroll
    for (int nt = 0; nt < 5; ++nt) {
        f32x4 acc = {0.f, 0.f, 0.f, 0.f};
        #pragma unroll
        for (int ks = 0; ks < 3; ++ks) {
            const unsigned short* bp =
                ws + ((size_t)(((w * 3 + ks) * 5 + nt) * 64 + l)) * 8;
            bf16x8 bfrag = *(const bf16x8*)bp;
            acc = __builtin_amdgcn_mfma_f32_16x16x32_bf16(
                      afrag[ks], bfrag, acc, 0, 0, 0);
        }
        // lane l holds D[m=(l>>4)*4+i][o = nt*16 + (l&15)]; max over m
        float m1 = fmaxf(fmaxf(acc[0], acc[1]), fmaxf(acc[2], acc[3]));
        m1 = fmaxf(m1, __shfl_xor(m1, 16));
        m1 = fmaxf(m1, __shfl_xor(m1, 32));
        if ((l & 48) == 0 && l < 16) {
            int oo = nt * 16 + l;
            out[(size_t)p * (W * O) + w * O + oo] = m1 + bc[w * O + oo];
        }
    }
}

// ============================================================================
// Fallback tier: R4 fused kernel (known-good) if ws too small for desc spill.
// ============================================================================
__global__ __launch_bounds__(64) void pack_wc_kernel(
    const float* __restrict__ Wc, unsigned short* __restrict__ wsB)
{
    const int f = blockIdx.x, l = threadIdx.x;
    const int w = f / 15, r = f % 15, ks = r / 5, nt = r % 5;
    const int g0 = ks * 32 + ((l >> 4) << 3);
    const int o  = nt * 16 + (l & 15);
    unsigned short v[8];
    #pragma unroll
    for (int i = 0; i < 8; ++i) {
        int g = g0 + i;
        v[i] = (g < G) ? f2bf(Wc[(w * G + g) * O + o]) : (unsigned short)0;
    }
    *(uint4*)(wsB + ((size_t)f * 64 + l) * 8) = *(const uint4*)v;
}

__global__ __launch_bounds__(320) void conv_kernel(
    const float* __restrict__ feat, const float* __restrict__ rho,
    const float* __restrict__ theta, const float* __restrict__ mask,
    const float* __restrict__ mu_rho, const float* __restrict__ mu_theta,
    const float* __restrict__ sig_rho, const float* __restrict__ sig_theta,
    const unsigned short* __restrict__ wsB, const float* __restrict__ bc,
    float* __restrict__ out)
{
    __shared__ float s_pt[V][8];
    __shared__ unsigned short s_descT[W][NROT][GPAD];
    __shared__ float s_red[W][64];

    const int tid = threadIdx.x;
    const int p = blockIdx.x;
    const int g = tid % G;
    const int j = tid / G;

    if (tid < V * W) {
        int v = tid / W, w = tid % W;
        s_pt[v][w] = feat[p * V * W + tid];
    }
    if (tid < V) {
        s_pt[tid][5] = rho[p * V + tid];
        s_pt[tid][6] = (mask[p * V + tid] != 0.0f) ? 0.0f : -1e30f;
        s_pt[tid][7] = theta[p * V + tid];
    }
    for (int i = tid; i < W * NROT * 8; i += 320) {
        int row = i >> 3, col = 40 + (i & 7);
        ((unsigned*)s_descT)[row * 48 + col] = 0u;
    }
    const int wchk = 1 + j;
    int pred = (mu_rho  [wchk * G + g] == mu_rho  [g]) &&
               (mu_theta[wchk * G + g] == mu_theta[g]) &&
               (sig_rho [wchk * G + g] == sig_rho [g]) &&
               (sig_theta[wchk * G + g] == sig_theta[g]);
    const int uni = __syncthreads_and(pred);

    const float kstep = 0.39269908169872414f;
    const float two_pi = 6.283185307179586f;
    const float inv_two_pi = 0.15915494309189535f;
    float koff[4];
    #pragma unroll
    for (int kk = 0; kk < 4; ++kk) koff[kk] = (float)(j * 4 + kk) * kstep;

    if (uni) {
        const float mu_r = mu_rho[g];
        const float sr   = sig_rho[g];
        const float c_sr = NLOG2E / (sr * sr + EPSV);
        const float mu_t = mu_theta[g];
        const float st   = sig_theta[g];
        const float c_st = NLOG2E / (st * st + EPSV);
        float den[4] = {0.f, 0.f, 0.f, 0.f};
        float num[5][4];
        #pragma unroll
        for (int w = 0; w < W; ++w)
            #pragma unroll
            for (int kk = 0; kk < 4; ++kk) num[w][kk] = 0.f;
        #pragma unroll 2
        for (int v = 0; v < V; ++v) {
            float4 flo = *(const float4*)(&s_pt[v][0]);
            float4 fhi = *(const float4*)(&s_pt[v][4]);
            float dr = fhi.y - mu_r;
            float argr = fmaf(dr * dr, c_sr, fhi.z);
            #pragma unroll
            for (int kk = 0; kk < 4; ++kk) {
                float x = fhi.w + koff[kk];
                x = x - floorf(x * inv_two_pi) * two_pi;
                float t = x - mu_t;
                float e = __builtin_amdgcn_exp2f(fmaf(t * t, c_st, argr));
                den[kk] += e;
                num[0][kk] = fmaf(e, flo.x, num[0][kk]);
                num[1][kk] = fmaf(e, flo.y, num[1][kk]);
                num[2][kk] = fmaf(e, flo.z, num[2][kk]);
                num[3][kk] = fmaf(e, flo.w, num[3][kk]);
                num[4][kk] = fmaf(e, fhi.x, num[4][kk]);
            }
        }
        float rd[4];
        #pragma unroll
        for (int kk = 0; kk < 4; ++kk)
            rd[kk] = __builtin_amdgcn_rcpf(den[kk] + EPSV);
        #pragma unroll
        for (int w = 0; w < W; ++w)
            #pragma unroll
            for (int kk = 0; kk < 4; ++kk)
                s_descT[w][j * 4 + kk][g] = f2bf(num[w][kk] * rd[kk]);
    } else {
        #pragma unroll 1
        for (int w = 0; w < W; ++w) {
            const float mu_r = mu_rho[w * G + g];
            const float sr   = sig_rho[w * G + g];
            const float c_sr = NLOG2E / (sr * sr + EPSV);
            const float mu_t = mu_theta[w * G + g];
            const float st   = sig_theta[w * G + g];
            const float c_st = NLOG2E / (st * st + EPSV);
            float den[4] = {0.f, 0.f, 0.f, 0.f};
            float nm[4]  = {0.f, 0.f, 0.f, 0.f};
            for (int v = 0; v < V; ++v) {
                float fw  = s_pt[v][w];
                float rv  = s_pt[v][5];
                float mrk = s_pt[v][6];
                float th  = s_pt[v][7];
                float dr = rv - mu_r;
                float argr = fmaf(dr * dr, c_sr, mrk);
                #pragma unroll
                for (int kk = 0; kk < 4; ++kk) {
                    float x = th + koff[kk];
                    x = x - floorf(x * inv_two_pi) * two_pi;
                    float t = x - mu_t;
                    float e = __builtin_amdgcn_exp2f(fmaf(t * t, c_st, argr));
                    den[kk] += e;
                    nm[kk] = fmaf(e, fw, nm[kk]);
                }
            }
            #pragma unroll
            for (int kk = 0; kk < 4; ++kk)
                s_descT[w][j * 4 + kk][g] =
                    f2bf(nm[kk] * __builtin_amdgcn_rcpf(den[kk] + EPSV));
        }
    }
    __syncthreads();
    {
        const int ww = tid >> 6;
        const int l  = tid & 63;
        bf16x8 afrag[3];
        #pragma unroll
        for (int ks = 0; ks < 3; ++ks)
            afrag[ks] = *(const bf16x8*)(&s_descT[ww][l & 15]
                                                [ks * 32 + ((l >> 4) << 3)]);
        #pragma unroll
        for (int nt = 0; nt < 5; ++nt) {
            f32x4 acc = {0.f, 0.f, 0.f, 0.f};
            #pragma unroll
            for (int ks = 0; ks < 3; ++ks) {
                const unsigned short* bp =
                    wsB + ((size_t)(((ww * 3 + ks) * 5 + nt) * 64 + l)) * 8;
                bf16x8 bfrag = *(const bf16x8*)bp;
                acc = __builtin_amdgcn_mfma_f32_16x16x32_bf16(
                          afrag[ks], bfrag, acc, 0, 0, 0);
            }
            float m1 = fmaxf(fmaxf(acc[0], acc[1]), fmaxf(acc[2], acc[3]));
            s_red[ww][l] = m1;
            float r0 = s_red[ww][l & 15];
            float r1 = s_red[ww][(l & 15) + 16];
            float r2 = s_red[ww][(l & 15) + 32];
            float r3 = s_red[ww][(l & 15) + 48];
            float mx = fmaxf(fmaxf(r0, r1), fmaxf(r2, r3));
            if (l < 16) {
                int oo = nt * 16 + l;
                out[p * (W * O) + ww * O + oo] = mx + bc[ww * O + oo];
            }
        }
    }
}

extern "C" void kernel_launch(void* const* d_in, const int* in_sizes, int n_in,
                              void* d_out, int out_size, void* d_ws, size_t ws_size,
                              hipStream_t stream) {
    const float* feat      = (const float*)d_in[0];
    const float* rho       = (const float*)d_in[1];
    const float* theta     = (const float*)d_in[2];
    const float* mask      = (const float*)d_in[3];
    const float* mu_rho    = (const float*)d_in[4];
    const float* mu_theta  = (const float*)d_in[5];
    const float* sig_rho   = (const float*)d_in[6];
    const float* sig_theta = (const float*)d_in[7];
    const float* Wc        = (const float*)d_in[8];
    const float* bc        = (const float*)d_in[9];
    float* outp            = (float*)d_out;

    const int np = in_sizes[1] / V;   // B*N points
    unsigned short* ws = (unsigned short*)d_ws;
    const size_t need =
        ((size_t)WSB_SHORTS + (size_t)np * W * NROT * GPAD) * sizeof(short);

    if (ws_size >= need) {
        desc_kernel<<<np + 8, 640, 0, stream>>>(feat, rho, theta, mask,
                                                mu_rho, mu_theta, sig_rho,
                                                sig_theta, Wc, ws, np);
        out_kernel<<<(np * W + 3) / 4, 256, 0, stream>>>(ws, bc, outp, np);
    } else {
        pack_wc_kernel<<<75, 64, 0, stream>>>(Wc, ws);
        conv_kernel<<<np, 320, 0, stream>>>(feat, rho, theta, mask, mu_rho,
                                            mu_theta, sig_rho, sig_theta,
                                            ws, bc, outp);
    }
}